// Round 1
// baseline (222.585 us; speedup 1.0000x reference)
//
#include <hip/hip_runtime.h>
#include <hip/hip_bf16.h>

#define NS 512
#define NB 2048
#define NT 32
#define NF 64
#define NH 128

// output float offsets: [leaf_xs (S,T,F)][leaf_y (S,T)][alphas (S,B,T)]
#define OY  ((size_t)NS * NT * NF)
#define OA  (OY + (size_t)NS * NT)

// ---------- mask layout detection: 1 = 1-byte bool, 0 = int32 ----------
__global__ void detect_layout_k(const unsigned char* m, int* flag) {
    __shared__ int any1;
    if (threadIdx.x == 0) any1 = 0;
    __syncthreads();
    for (int i = threadIdx.x; i < 4096; i += blockDim.x)
        if ((i & 3) != 0 && m[i] != 0) any1 = 1;   // benign same-value race
    __syncthreads();
    if (threadIdx.x == 0) *flag = any1;
}

// ---------- pack mask to bits: word w covers flat indices [w*64, w*64+64) ----------
// flat = s*B*T + b*T + t; per row s: u32 word index == b, bit == t.
__global__ __launch_bounds__(256) void pack_mask_k(const void* mask, const int* flag,
                                                   unsigned long long* pm, int nwords) {
    const int isbyte = *flag;
    const int lane = threadIdx.x & 63;
    const int gw = (blockIdx.x * blockDim.x + threadIdx.x) >> 6;
    const int nw = (gridDim.x * blockDim.x) >> 6;
    if (isbyte) {
        const unsigned char* mb = (const unsigned char*)mask;
        for (int w = gw; w < nwords; w += nw) {
            unsigned char v = mb[(size_t)w * 64 + lane];
            unsigned long long bits = __ballot(v != 0);
            if (lane == 0) pm[w] = bits;
        }
    } else {
        const int* mi = (const int*)mask;
        for (int w = gw; w < nwords; w += nw) {
            int v = mi[(size_t)w * 64 + lane];
            unsigned long long bits = __ballot(v != 0);
            if (lane == 0) pm[w] = bits;
        }
    }
}

// ---------- encode rows 0..511 = X, 512..2559 = background_X ----------
__global__ __launch_bounds__(128) void encode_k(const float* __restrict__ X,
        const float* __restrict__ bgX, const float* __restrict__ W1,
        const float* __restrict__ b1, const float* __restrict__ W2,
        const float* __restrict__ b2, float* __restrict__ enc) {
    __shared__ float xr[NF];
    __shared__ float hr[NH];
    const int row = blockIdx.x;
    const int j = threadIdx.x;
    const float* src = (row < NS) ? (X + (size_t)row * NF) : (bgX + (size_t)(row - NS) * NF);
    if (j < NF) xr[j] = src[j];
    __syncthreads();
    float acc = b1[j];
    #pragma unroll 8
    for (int f = 0; f < NF; ++f) acc = fmaf(xr[f], W1[f * NH + j], acc);
    hr[j] = tanhf(acc);
    __syncthreads();
    float acc2 = b2[j];
    #pragma unroll 8
    for (int k = 0; k < NH; ++k) acc2 = fmaf(hr[k], W2[k * NH + j], acc2);
    enc[(size_t)row * NH + j] = acc2;
}

// ---------- dots = X_enc @ bg_enc^T, 64x64 tiles, K=128 in two 64-slices ----------
__global__ __launch_bounds__(256) void dots_k(const float* __restrict__ Xe,
        const float* __restrict__ Be, float* __restrict__ dots) {
    __shared__ float At[64 * 68];
    __shared__ float Bt[64 * 68];
    const int s0 = blockIdx.y * 64, b0 = blockIdx.x * 64;
    const int tid = threadIdx.x;
    const int ts = tid & 15, tb = tid >> 4;
    float acc[4][4] = {};
    for (int kt = 0; kt < 2; ++kt) {
        __syncthreads();
        #pragma unroll
        for (int it = 0; it < 4; ++it) {
            int idx = tid * 4 + it * 1024;
            int r = idx >> 6, k = idx & 63;
            *(float4*)(&At[r * 68 + k]) = *(const float4*)(Xe + (size_t)(s0 + r) * NH + kt * 64 + k);
            *(float4*)(&Bt[r * 68 + k]) = *(const float4*)(Be + (size_t)(b0 + r) * NH + kt * 64 + k);
        }
        __syncthreads();
        #pragma unroll 4
        for (int k = 0; k < 64; ++k) {
            float a[4], bv[4];
            #pragma unroll
            for (int i = 0; i < 4; ++i) a[i] = At[(ts + 16 * i) * 68 + k];
            #pragma unroll
            for (int jj = 0; jj < 4; ++jj) bv[jj] = Bt[(tb * 4 + jj) * 68 + k];
            #pragma unroll
            for (int i = 0; i < 4; ++i)
                #pragma unroll
                for (int jj = 0; jj < 4; ++jj)
                    acc[i][jj] = fmaf(a[i], bv[jj], acc[i][jj]);
        }
    }
    #pragma unroll
    for (int i = 0; i < 4; ++i) {
        float4 v = make_float4(acc[i][0], acc[i][1], acc[i][2], acc[i][3]);
        *(float4*)(&dots[(size_t)(s0 + ts + 16 * i) * NB + b0 + tb * 4]) = v;
    }
}

// ---------- fused softmax + alphas + leaf_y + leaf_xs, one block per s ----------
__global__ __launch_bounds__(256) void fused_k(const float* __restrict__ dots,
        const unsigned long long* __restrict__ pmask,
        const float* __restrict__ bgX, const float* __restrict__ bgy,
        float* __restrict__ out) {
    __shared__ float smem[12832];                        // 51,328 B
    float* e_lds = smem;                                 // 2048: dots -> exp
    unsigned int* mrow = (unsigned int*)(smem + 2048);   // 2048 u32: mrow[b] bit t
    float* ylds = smem + 4096;                           // 2048: bg_y
    float* p_lds = smem + 6144;                          // 64 x 32 alphas chunk
    float* xs_lds = smem + 8192;                         // 64 x 64 bgX chunk
    float* red  = smem + 12288;                          // 256
    float* red2 = smem + 12544;                          // 256
    float* rden = smem + 12800;                          // 32

    const int s = blockIdx.x;
    const int tid = threadIdx.x;
    const int t = tid & 31, g = tid >> 5;

    // stage dots row (+ per-thread max), packed mask row, bg_y
    const float* drow = dots + (size_t)s * NB;
    float4 d0 = *(const float4*)(drow + tid * 8);
    float4 d1 = *(const float4*)(drow + tid * 8 + 4);
    *(float4*)(&e_lds[tid * 8]) = d0;
    *(float4*)(&e_lds[tid * 8 + 4]) = d1;
    red[tid] = fmaxf(fmaxf(fmaxf(d0.x, d0.y), fmaxf(d0.z, d0.w)),
                     fmaxf(fmaxf(d1.x, d1.y), fmaxf(d1.z, d1.w)));
    const uint4* pmrow = (const uint4*)((const unsigned int*)pmask + (size_t)s * 2048);
    #pragma unroll
    for (int it = 0; it < 2; ++it)
        *(uint4*)(&mrow[(tid + it * 256) * 4]) = pmrow[tid + it * 256];
    #pragma unroll
    for (int it = 0; it < 2; ++it)
        *(float4*)(&ylds[(tid + it * 256) * 4]) = *(const float4*)(bgy + (tid + it * 256) * 4);
    __syncthreads();
    for (int off = 128; off > 0; off >>= 1) {
        if (tid < off) red[tid] = fmaxf(red[tid], red[tid + off]);
        __syncthreads();
    }
    const float Ms = red[0];
    #pragma unroll
    for (int q = 0; q < 8; ++q)
        e_lds[tid * 8 + q] = __expf(e_lds[tid * 8 + q] - Ms);
    __syncthreads();

    // per-t denominator + leaf_y (thread = (t, g), g covers 256 b's blocked)
    float dsum = 0.f, ysum = 0.f;
    #pragma unroll 4
    for (int i = 0; i < 256; ++i) {
        int b = g * 256 + i;
        float sel = (float)((mrow[b] >> t) & 1u);
        float e = sel * e_lds[b];
        dsum += e;
        ysum = fmaf(e, ylds[b], ysum);
    }
    red[tid] = dsum;
    red2[tid] = ysum;
    __syncthreads();
    if (tid < 32) {
        float den = 0.f, yv = 0.f;
        #pragma unroll
        for (int gg = 0; gg < 8; ++gg) { den += red[gg * 32 + tid]; yv += red2[gg * 32 + tid]; }
        float rd = den > 0.f ? 1.f / den : 0.f;
        rden[tid] = rd;
        out[OY + (size_t)s * NT + tid] = yv * rd;
    }
    __syncthreads();

    // chunked: alphas write + einsum accumulate (8t x 8f register tile per thread)
    const int tt = tid & 3, ff = (tid >> 2) & 7;   // bg group == g
    const float rdt = rden[t];
    float acc[8][8] = {};
    float* aout = out + OA + (size_t)s * NB * NT;
    for (int c = 0; c < 32; ++c) {
        const int b0 = c * 64;
        #pragma unroll
        for (int i = 0; i < 8; ++i) {
            int bl = g + 8 * i;
            int b = b0 + bl;
            float sel = (float)((mrow[b] >> t) & 1u);
            float alpha = sel * e_lds[b] * rdt;
            p_lds[bl * 32 + t] = alpha;
            aout[(size_t)b * NT + t] = alpha;          // coalesced 256B/wave
        }
        #pragma unroll
        for (int it = 0; it < 4; ++it) {
            int idx = tid * 4 + it * 1024;
            *(float4*)(&xs_lds[idx]) = *(const float4*)(bgX + (size_t)b0 * NF + idx);
        }
        __syncthreads();
        #pragma unroll
        for (int bb = 0; bb < 8; ++bb) {
            int bl = g + 8 * bb;
            float pv[8], xv[8];
            #pragma unroll
            for (int j = 0; j < 8; ++j) pv[j] = p_lds[bl * 32 + tt * 8 + j];
            #pragma unroll
            for (int k = 0; k < 8; ++k) xv[k] = xs_lds[bl * 64 + ff * 8 + k];
            #pragma unroll
            for (int j = 0; j < 8; ++j)
                #pragma unroll
                for (int k = 0; k < 8; ++k)
                    acc[j][k] = fmaf(pv[j], xv[k], acc[j][k]);
        }
        __syncthreads();
    }

    // tree-reduce the 8 bg-group partials, then write leaf_xs
    const int oidx = tt * 8 * 64 + ff * 8;
    float* scratch = smem;   // e/mrow/y/p regions are dead now: 8192 floats
    if (g >= 4) {
        #pragma unroll
        for (int j = 0; j < 8; ++j)
            #pragma unroll
            for (int k = 0; k < 8; ++k)
                scratch[(g - 4) * 2048 + oidx + j * 64 + k] = acc[j][k];
    }
    __syncthreads();
    if (g < 4) {
        #pragma unroll
        for (int j = 0; j < 8; ++j)
            #pragma unroll
            for (int k = 0; k < 8; ++k)
                acc[j][k] += scratch[g * 2048 + oidx + j * 64 + k];
    }
    __syncthreads();
    if (g == 2 || g == 3) {
        #pragma unroll
        for (int j = 0; j < 8; ++j)
            #pragma unroll
            for (int k = 0; k < 8; ++k)
                scratch[(g - 2) * 2048 + oidx + j * 64 + k] = acc[j][k];
    }
    __syncthreads();
    if (g < 2) {
        #pragma unroll
        for (int j = 0; j < 8; ++j)
            #pragma unroll
            for (int k = 0; k < 8; ++k)
                acc[j][k] += scratch[g * 2048 + oidx + j * 64 + k];
    }
    __syncthreads();
    if (g == 1) {
        #pragma unroll
        for (int j = 0; j < 8; ++j)
            #pragma unroll
            for (int k = 0; k < 8; ++k)
                scratch[oidx + j * 64 + k] = acc[j][k];
    }
    __syncthreads();
    if (g == 0) {
        #pragma unroll
        for (int j = 0; j < 8; ++j) {
            #pragma unroll
            for (int k = 0; k < 8; ++k)
                acc[j][k] += scratch[oidx + j * 64 + k];
            float4 v0 = make_float4(acc[j][0], acc[j][1], acc[j][2], acc[j][3]);
            float4 v1 = make_float4(acc[j][4], acc[j][5], acc[j][6], acc[j][7]);
            *(float4*)(&out[(size_t)s * NT * NF + oidx + j * 64]) = v0;
            *(float4*)(&out[(size_t)s * NT * NF + oidx + j * 64 + 4]) = v1;
        }
    }
}

extern "C" void kernel_launch(void* const* d_in, const int* in_sizes, int n_in,
                              void* d_out, int out_size, void* d_ws, size_t ws_size,
                              hipStream_t stream) {
    (void)in_sizes; (void)n_in; (void)out_size; (void)ws_size;
    const float* X   = (const float*)d_in[0];
    const float* bgX = (const float*)d_in[1];
    const float* bgy = (const float*)d_in[2];
    const void*  nh  = d_in[3];
    const float* W1  = (const float*)d_in[4];
    const float* b1v = (const float*)d_in[5];
    const float* W2  = (const float*)d_in[6];
    const float* b2v = (const float*)d_in[7];
    float* out = (float*)d_out;
    char* ws = (char*)d_ws;

    // ws layout (bytes): [flag @0][enc @4096: 2560*128 f32][dots: 512*2048 f32][pmask: 524288 u64]
    int* flag = (int*)ws;
    float* enc = (float*)(ws + 4096);
    float* Xe = enc;
    float* Be = enc + (size_t)NS * NH;
    float* dots = (float*)(ws + 4096 + (size_t)(NS + NB) * NH * 4);
    unsigned long long* pmask = (unsigned long long*)((char*)dots + (size_t)NS * NB * 4);

    detect_layout_k<<<1, 256, 0, stream>>>((const unsigned char*)nh, flag);
    pack_mask_k<<<512, 256, 0, stream>>>(nh, flag, pmask, NS * NB * NT / 64);
    encode_k<<<NS + NB, 128, 0, stream>>>(X, bgX, W1, b1v, W2, b2v, enc);
    dots_k<<<dim3(NB / 64, NS / 64), 256, 0, stream>>>(Xe, Be, dots);
    fused_k<<<NS, 256, 0, stream>>>(dots, pmask, bgX, bgy, out);
}

// Round 2
// 217.422 us; speedup vs baseline: 1.0237x; 1.0237x over previous
//
#include <hip/hip_runtime.h>
#include <hip/hip_bf16.h>

#define NS 512
#define NB 2048
#define NT 32
#define NF 64
#define NH 128

// output float offsets: [leaf_xs (S,T,F)][leaf_y (S,T)][alphas (S,B,T)]
#define OY  ((size_t)NS * NT * NF)
#define OA  (OY + (size_t)NS * NT)

// ---------- mask layout detection: 1 = 1-byte bool, 0 = int32 ----------
__global__ void detect_layout_k(const unsigned char* m, int* flag) {
    __shared__ int any1;
    if (threadIdx.x == 0) any1 = 0;
    __syncthreads();
    for (int i = threadIdx.x; i < 4096; i += blockDim.x)
        if ((i & 3) != 0 && m[i] != 0) any1 = 1;   // benign same-value race
    __syncthreads();
    if (threadIdx.x == 0) *flag = any1;
}

// ---------- pack mask to bits: word w covers flat indices [w*64, w*64+64) ----------
// flat = s*B*T + b*T + t; per row s: u32 word index == b, bit == t.
__global__ __launch_bounds__(256) void pack_mask_k(const void* mask, const int* flag,
                                                   unsigned long long* pm, int nwords) {
    const int isbyte = *flag;
    const int lane = threadIdx.x & 63;
    const int gw = (blockIdx.x * blockDim.x + threadIdx.x) >> 6;
    const int nw = (gridDim.x * blockDim.x) >> 6;
    if (isbyte) {
        const unsigned char* mb = (const unsigned char*)mask;
        for (int w = gw; w < nwords; w += nw) {
            unsigned char v = mb[(size_t)w * 64 + lane];
            unsigned long long bits = __ballot(v != 0);
            if (lane == 0) pm[w] = bits;
        }
    } else {
        const int* mi = (const int*)mask;
        for (int w = gw; w < nwords; w += nw) {
            int v = mi[(size_t)w * 64 + lane];
            unsigned long long bits = __ballot(v != 0);
            if (lane == 0) pm[w] = bits;
        }
    }
}

// ---------- encode rows 0..511 = X, 512..2559 = background_X ----------
__global__ __launch_bounds__(128) void encode_k(const float* __restrict__ X,
        const float* __restrict__ bgX, const float* __restrict__ W1,
        const float* __restrict__ b1, const float* __restrict__ W2,
        const float* __restrict__ b2, float* __restrict__ enc) {
    __shared__ float xr[NF];
    __shared__ float hr[NH];
    const int row = blockIdx.x;
    const int j = threadIdx.x;
    const float* src = (row < NS) ? (X + (size_t)row * NF) : (bgX + (size_t)(row - NS) * NF);
    if (j < NF) xr[j] = src[j];
    __syncthreads();
    float acc = b1[j];
    #pragma unroll 8
    for (int f = 0; f < NF; ++f) acc = fmaf(xr[f], W1[f * NH + j], acc);
    hr[j] = tanhf(acc);
    __syncthreads();
    float acc2 = b2[j];
    #pragma unroll 8
    for (int k = 0; k < NH; ++k) acc2 = fmaf(hr[k], W2[k * NH + j], acc2);
    enc[(size_t)row * NH + j] = acc2;
}

// ---------- dots = X_enc @ bg_enc^T, 64x64 tiles, K=128 in two 64-slices ----------
__global__ __launch_bounds__(256) void dots_k(const float* __restrict__ Xe,
        const float* __restrict__ Be, float* __restrict__ dots) {
    __shared__ float At[64 * 68];
    __shared__ float Bt[64 * 68];
    const int s0 = blockIdx.y * 64, b0 = blockIdx.x * 64;
    const int tid = threadIdx.x;
    const int ts = tid & 15, tb = tid >> 4;
    float acc[4][4] = {};
    for (int kt = 0; kt < 2; ++kt) {
        __syncthreads();
        #pragma unroll
        for (int it = 0; it < 4; ++it) {
            int idx = tid * 4 + it * 1024;
            int r = idx >> 6, k = idx & 63;
            *(float4*)(&At[r * 68 + k]) = *(const float4*)(Xe + (size_t)(s0 + r) * NH + kt * 64 + k);
            *(float4*)(&Bt[r * 68 + k]) = *(const float4*)(Be + (size_t)(b0 + r) * NH + kt * 64 + k);
        }
        __syncthreads();
        #pragma unroll 4
        for (int k = 0; k < 64; ++k) {
            float a[4], bv[4];
            #pragma unroll
            for (int i = 0; i < 4; ++i) a[i] = At[(ts + 16 * i) * 68 + k];
            #pragma unroll
            for (int jj = 0; jj < 4; ++jj) bv[jj] = Bt[(tb * 4 + jj) * 68 + k];
            #pragma unroll
            for (int i = 0; i < 4; ++i)
                #pragma unroll
                for (int jj = 0; jj < 4; ++jj)
                    acc[i][jj] = fmaf(a[i], bv[jj], acc[i][jj]);
        }
    }
    #pragma unroll
    for (int i = 0; i < 4; ++i) {
        float4 v = make_float4(acc[i][0], acc[i][1], acc[i][2], acc[i][3]);
        *(float4*)(&dots[(size_t)(s0 + ts + 16 * i) * NB + b0 + tb * 4]) = v;
    }
}

// ---------- fused softmax + alphas + leaf_y + leaf_xs, one block per s ----------
__global__ __launch_bounds__(256) void fused_k(const float* __restrict__ dots,
        const unsigned long long* __restrict__ pmask,
        const float* __restrict__ bgX, const float* __restrict__ bgy,
        float* __restrict__ out) {
    __shared__ float smem[12832];                        // 51,328 B
    float* e_lds = smem;                                 // 2048: dots -> exp
    unsigned int* mrow = (unsigned int*)(smem + 2048);   // 2048 u32: mrow[b] bit t
    float* ylds = smem + 4096;                           // 2048: bg_y
    float* p_lds = smem + 6144;                          // 64 x 32 alphas chunk
    float* xs_lds = smem + 8192;                         // 64 x 64 bgX chunk
    float* red  = smem + 12288;                          // 256
    float* red2 = smem + 12544;                          // 256
    float* rden = smem + 12800;                          // 32

    const int s = blockIdx.x;
    const int tid = threadIdx.x;
    const int t = tid & 31, g = tid >> 5;

    // stage dots row (+ per-thread max), packed mask row, bg_y
    const float* drow = dots + (size_t)s * NB;
    float4 d0 = *(const float4*)(drow + tid * 8);
    float4 d1 = *(const float4*)(drow + tid * 8 + 4);
    *(float4*)(&e_lds[tid * 8]) = d0;
    *(float4*)(&e_lds[tid * 8 + 4]) = d1;
    red[tid] = fmaxf(fmaxf(fmaxf(d0.x, d0.y), fmaxf(d0.z, d0.w)),
                     fmaxf(fmaxf(d1.x, d1.y), fmaxf(d1.z, d1.w)));
    const uint4* pmrow = (const uint4*)((const unsigned int*)pmask + (size_t)s * 2048);
    #pragma unroll
    for (int it = 0; it < 2; ++it)
        *(uint4*)(&mrow[(tid + it * 256) * 4]) = pmrow[tid + it * 256];
    #pragma unroll
    for (int it = 0; it < 2; ++it)
        *(float4*)(&ylds[(tid + it * 256) * 4]) = *(const float4*)(bgy + (tid + it * 256) * 4);
    __syncthreads();
    for (int off = 128; off > 0; off >>= 1) {
        if (tid < off) red[tid] = fmaxf(red[tid], red[tid + off]);
        __syncthreads();
    }
    const float Ms = red[0];
    #pragma unroll
    for (int q = 0; q < 8; ++q)
        e_lds[tid * 8 + q] = __expf(e_lds[tid * 8 + q] - Ms);
    __syncthreads();

    // per-t denominator + leaf_y (thread = (t, g), g covers 256 b's blocked)
    float dsum = 0.f, ysum = 0.f;
    #pragma unroll 4
    for (int i = 0; i < 256; ++i) {
        int b = g * 256 + i;
        float sel = (float)((mrow[b] >> t) & 1u);
        float e = sel * e_lds[b];
        dsum += e;
        ysum = fmaf(e, ylds[b], ysum);
    }
    red[tid] = dsum;
    red2[tid] = ysum;
    __syncthreads();
    if (tid < 32) {
        float den = 0.f, yv = 0.f;
        #pragma unroll
        for (int gg = 0; gg < 8; ++gg) { den += red[gg * 32 + tid]; yv += red2[gg * 32 + tid]; }
        float rd = den > 0.f ? 1.f / den : 0.f;
        rden[tid] = rd;
        out[OY + (size_t)s * NT + tid] = yv * rd;
    }
    __syncthreads();

    // chunked: alphas write + einsum accumulate (8t x 8f register tile per thread)
    const int tt = tid & 3, ff = (tid >> 2) & 7;   // bg group == g
    const float rdt = rden[t];
    float acc[8][8] = {};
    float* aout = out + OA + (size_t)s * NB * NT;
    for (int c = 0; c < 32; ++c) {
        const int b0 = c * 64;
        #pragma unroll
        for (int i = 0; i < 8; ++i) {
            int bl = g + 8 * i;
            int b = b0 + bl;
            float sel = (float)((mrow[b] >> t) & 1u);
            float alpha = sel * e_lds[b] * rdt;
            p_lds[bl * 32 + t] = alpha;
            aout[(size_t)b * NT + t] = alpha;          // coalesced 256B/wave
        }
        #pragma unroll
        for (int it = 0; it < 4; ++it) {
            int idx = tid * 4 + it * 1024;
            *(float4*)(&xs_lds[idx]) = *(const float4*)(bgX + (size_t)b0 * NF + idx);
        }
        __syncthreads();
        #pragma unroll
        for (int bb = 0; bb < 8; ++bb) {
            int bl = g + 8 * bb;
            float pv[8], xv[8];
            #pragma unroll
            for (int j = 0; j < 8; ++j) pv[j] = p_lds[bl * 32 + tt * 8 + j];
            #pragma unroll
            for (int k = 0; k < 8; ++k) xv[k] = xs_lds[bl * 64 + ff * 8 + k];
            #pragma unroll
            for (int j = 0; j < 8; ++j)
                #pragma unroll
                for (int k = 0; k < 8; ++k)
                    acc[j][k] = fmaf(pv[j], xv[k], acc[j][k]);
        }
        __syncthreads();
    }

    // tree-reduce the 8 bg-group partials, then write leaf_xs
    const int oidx = tt * 8 * 64 + ff * 8;
    float* scratch = smem;   // e/mrow/y/p regions are dead now: 8192 floats
    if (g >= 4) {
        #pragma unroll
        for (int j = 0; j < 8; ++j)
            #pragma unroll
            for (int k = 0; k < 8; ++k)
                scratch[(g - 4) * 2048 + oidx + j * 64 + k] = acc[j][k];
    }
    __syncthreads();
    if (g < 4) {
        #pragma unroll
        for (int j = 0; j < 8; ++j)
            #pragma unroll
            for (int k = 0; k < 8; ++k)
                acc[j][k] += scratch[g * 2048 + oidx + j * 64 + k];
    }
    __syncthreads();
    if (g == 2 || g == 3) {
        #pragma unroll
        for (int j = 0; j < 8; ++j)
            #pragma unroll
            for (int k = 0; k < 8; ++k)
                scratch[(g - 2) * 2048 + oidx + j * 64 + k] = acc[j][k];
    }
    __syncthreads();
    if (g < 2) {
        #pragma unroll
        for (int j = 0; j < 8; ++j)
            #pragma unroll
            for (int k = 0; k < 8; ++k)
                acc[j][k] += scratch[g * 2048 + oidx + j * 64 + k];
    }
    __syncthreads();
    if (g == 1) {
        #pragma unroll
        for (int j = 0; j < 8; ++j)
            #pragma unroll
            for (int k = 0; k < 8; ++k)
                scratch[oidx + j * 64 + k] = acc[j][k];
    }
    __syncthreads();
    if (g == 0) {
        #pragma unroll
        for (int j = 0; j < 8; ++j) {
            #pragma unroll
            for (int k = 0; k < 8; ++k)
                acc[j][k] += scratch[oidx + j * 64 + k];
            float4 v0 = make_float4(acc[j][0], acc[j][1], acc[j][2], acc[j][3]);
            float4 v1 = make_float4(acc[j][4], acc[j][5], acc[j][6], acc[j][7]);
            *(float4*)(&out[(size_t)s * NT * NF + oidx + j * 64]) = v0;
            *(float4*)(&out[(size_t)s * NT * NF + oidx + j * 64 + 4]) = v1;
        }
    }
}

extern "C" void kernel_launch(void* const* d_in, const int* in_sizes, int n_in,
                              void* d_out, int out_size, void* d_ws, size_t ws_size,
                              hipStream_t stream) {
    (void)in_sizes; (void)n_in; (void)out_size; (void)ws_size;
    const float* X   = (const float*)d_in[0];
    const float* bgX = (const float*)d_in[1];
    const float* bgy = (const float*)d_in[2];
    const void*  nh  = d_in[3];
    const float* W1  = (const float*)d_in[4];
    const float* b1v = (const float*)d_in[5];
    const float* W2  = (const float*)d_in[6];
    const float* b2v = (const float*)d_in[7];
    float* out = (float*)d_out;
    char* ws = (char*)d_ws;

    // ws layout (bytes): [flag @0][enc @4096: 2560*128 f32][dots: 512*2048 f32][pmask: 524288 u64]
    int* flag = (int*)ws;
    float* enc = (float*)(ws + 4096);
    float* Xe = enc;
    float* Be = enc + (size_t)NS * NH;
    float* dots = (float*)(ws + 4096 + (size_t)(NS + NB) * NH * 4);
    unsigned long long* pmask = (unsigned long long*)((char*)dots + (size_t)NS * NB * 4);

    detect_layout_k<<<1, 256, 0, stream>>>((const unsigned char*)nh, flag);
    pack_mask_k<<<512, 256, 0, stream>>>(nh, flag, pmask, NS * NB * NT / 64);
    encode_k<<<NS + NB, 128, 0, stream>>>(X, bgX, W1, b1v, W2, b2v, enc);
    dots_k<<<dim3(NB / 64, NS / 64), 256, 0, stream>>>(Xe, Be, dots);
    fused_k<<<NS, 256, 0, stream>>>(dots, pmask, bgX, bgy, out);
}

// Round 3
// 133.510 us; speedup vs baseline: 1.6672x; 1.6285x over previous
//
#include <hip/hip_runtime.h>
#include <hip/hip_bf16.h>

#define NS 512
#define NB 2048
#define NT 32
#define NF 64
#define NH 128

// output float offsets: [leaf_xs (S,T,F)][leaf_y (S,T)][alphas (S,B,T)]
#define OY  ((size_t)NS * NT * NF)
#define OA  (OY + (size_t)NS * NT)

// ---------- mask layout detection: 1 = 1-byte bool, 0 = int32 ----------
__global__ void detect_layout_k(const unsigned char* m, int* flag) {
    __shared__ int any1;
    if (threadIdx.x == 0) any1 = 0;
    __syncthreads();
    for (int i = threadIdx.x; i < 4096; i += blockDim.x)
        if ((i & 3) != 0 && m[i] != 0) any1 = 1;   // benign same-value race
    __syncthreads();
    if (threadIdx.x == 0) *flag = any1;
}

// bit j of result = (byte j of v != 0), j in [0,16)
__device__ __forceinline__ unsigned int pack16_bytes(uint4 v) {
    unsigned int r = 0;
    unsigned int xs[4] = {v.x, v.y, v.z, v.w};
    #pragma unroll
    for (int i = 0; i < 4; ++i) {
        unsigned int x = xs[i];
        unsigned int t = (x | ((x & 0x7F7F7F7Fu) + 0x7F7F7F7Fu)) & 0x80808080u;
        t >>= 7;                                  // nonzero flags at bits 0,8,16,24
        unsigned int n = (t | (t >> 7) | (t >> 14) | (t >> 21)) & 0xFu;
        r |= n << (i * 4);
    }
    return r;
}

// ---------- pack mask to bits: word w covers flat indices [w*64, w*64+64) ----------
// flat = s*B*T + b*T + t; per row s: u32 word index == b, bit == t.
// One thread per output word: 64 B (byte mask) as 4x uint4, fully in-register pack.
__global__ __launch_bounds__(256) void pack_mask_k(const void* mask, const int* flag,
                                                   unsigned long long* pm, int nwords) {
    const int w = blockIdx.x * blockDim.x + threadIdx.x;
    if (w >= nwords) return;
    if (*flag) {                                   // 1-byte bool layout
        const uint4* mb = (const uint4*)mask;
        uint4 q0 = mb[(size_t)w * 4 + 0];
        uint4 q1 = mb[(size_t)w * 4 + 1];
        uint4 q2 = mb[(size_t)w * 4 + 2];
        uint4 q3 = mb[(size_t)w * 4 + 3];
        unsigned long long r =  (unsigned long long)pack16_bytes(q0)
                             | ((unsigned long long)pack16_bytes(q1) << 16)
                             | ((unsigned long long)pack16_bytes(q2) << 32)
                             | ((unsigned long long)pack16_bytes(q3) << 48);
        pm[w] = r;
    } else {                                       // int32 layout
        const uint4* mi = (const uint4*)mask;
        unsigned long long r = 0;
        #pragma unroll
        for (int i = 0; i < 16; ++i) {
            uint4 v = mi[(size_t)w * 16 + i];
            unsigned int b = (v.x ? 1u : 0u) | (v.y ? 2u : 0u) |
                             (v.z ? 4u : 0u) | (v.w ? 8u : 0u);
            r |= (unsigned long long)b << (i * 4);
        }
        pm[w] = r;
    }
}

// ---------- encode rows 0..511 = X, 512..2559 = background_X ----------
__global__ __launch_bounds__(128) void encode_k(const float* __restrict__ X,
        const float* __restrict__ bgX, const float* __restrict__ W1,
        const float* __restrict__ b1, const float* __restrict__ W2,
        const float* __restrict__ b2, float* __restrict__ enc) {
    __shared__ float xr[NF];
    __shared__ float hr[NH];
    const int row = blockIdx.x;
    const int j = threadIdx.x;
    const float* src = (row < NS) ? (X + (size_t)row * NF) : (bgX + (size_t)(row - NS) * NF);
    if (j < NF) xr[j] = src[j];
    __syncthreads();
    float acc = b1[j];
    #pragma unroll 8
    for (int f = 0; f < NF; ++f) acc = fmaf(xr[f], W1[f * NH + j], acc);
    hr[j] = tanhf(acc);
    __syncthreads();
    float acc2 = b2[j];
    #pragma unroll 8
    for (int k = 0; k < NH; ++k) acc2 = fmaf(hr[k], W2[k * NH + j], acc2);
    enc[(size_t)row * NH + j] = acc2;
}

// ---------- dots = X_enc @ bg_enc^T, 64x64 tiles, K=128 in two 64-slices ----------
__global__ __launch_bounds__(256) void dots_k(const float* __restrict__ Xe,
        const float* __restrict__ Be, float* __restrict__ dots) {
    __shared__ float At[64 * 68];
    __shared__ float Bt[64 * 68];
    const int s0 = blockIdx.y * 64, b0 = blockIdx.x * 64;
    const int tid = threadIdx.x;
    const int ts = tid & 15, tb = tid >> 4;
    float acc[4][4] = {};
    for (int kt = 0; kt < 2; ++kt) {
        __syncthreads();
        #pragma unroll
        for (int it = 0; it < 4; ++it) {
            int idx = tid * 4 + it * 1024;
            int r = idx >> 6, k = idx & 63;
            *(float4*)(&At[r * 68 + k]) = *(const float4*)(Xe + (size_t)(s0 + r) * NH + kt * 64 + k);
            *(float4*)(&Bt[r * 68 + k]) = *(const float4*)(Be + (size_t)(b0 + r) * NH + kt * 64 + k);
        }
        __syncthreads();
        #pragma unroll 4
        for (int k = 0; k < 64; ++k) {
            float a[4], bv[4];
            #pragma unroll
            for (int i = 0; i < 4; ++i) a[i] = At[(ts + 16 * i) * 68 + k];
            #pragma unroll
            for (int jj = 0; jj < 4; ++jj) bv[jj] = Bt[(tb * 4 + jj) * 68 + k];
            #pragma unroll
            for (int i = 0; i < 4; ++i)
                #pragma unroll
                for (int jj = 0; jj < 4; ++jj)
                    acc[i][jj] = fmaf(a[i], bv[jj], acc[i][jj]);
        }
    }
    #pragma unroll
    for (int i = 0; i < 4; ++i) {
        float4 v = make_float4(acc[i][0], acc[i][1], acc[i][2], acc[i][3]);
        *(float4*)(&dots[(size_t)(s0 + ts + 16 * i) * NB + b0 + tb * 4]) = v;
    }
}

// ---------- fused softmax + alphas + leaf_y + leaf_xs, one block per s ----------
__global__ __launch_bounds__(256) void fused_k(const float* __restrict__ dots,
        const unsigned long long* __restrict__ pmask,
        const float* __restrict__ bgX, const float* __restrict__ bgy,
        float* __restrict__ out) {
    __shared__ float smem[12832];                        // 51,328 B
    float* e_lds = smem;                                 // 2048: dots -> exp
    unsigned int* mrow = (unsigned int*)(smem + 2048);   // 2048 u32: mrow[b] bit t
    float* ylds = smem + 4096;                           // 2048: bg_y
    float* p_lds = smem + 6144;                          // 64 x 32 alphas chunk
    float* xs_lds = smem + 8192;                         // 64 x 64 bgX chunk
    float* red  = smem + 12288;                          // 256
    float* red2 = smem + 12544;                          // 256
    float* rden = smem + 12800;                          // 32

    const int s = blockIdx.x;
    const int tid = threadIdx.x;
    const int t = tid & 31, g = tid >> 5;

    // stage dots row (+ per-thread max), packed mask row, bg_y
    const float* drow = dots + (size_t)s * NB;
    float4 d0 = *(const float4*)(drow + tid * 8);
    float4 d1 = *(const float4*)(drow + tid * 8 + 4);
    *(float4*)(&e_lds[tid * 8]) = d0;
    *(float4*)(&e_lds[tid * 8 + 4]) = d1;
    red[tid] = fmaxf(fmaxf(fmaxf(d0.x, d0.y), fmaxf(d0.z, d0.w)),
                     fmaxf(fmaxf(d1.x, d1.y), fmaxf(d1.z, d1.w)));
    const uint4* pmrow = (const uint4*)((const unsigned int*)pmask + (size_t)s * 2048);
    #pragma unroll
    for (int it = 0; it < 2; ++it)
        *(uint4*)(&mrow[(tid + it * 256) * 4]) = pmrow[tid + it * 256];
    #pragma unroll
    for (int it = 0; it < 2; ++it)
        *(float4*)(&ylds[(tid + it * 256) * 4]) = *(const float4*)(bgy + (tid + it * 256) * 4);
    __syncthreads();
    for (int off = 128; off > 0; off >>= 1) {
        if (tid < off) red[tid] = fmaxf(red[tid], red[tid + off]);
        __syncthreads();
    }
    const float Ms = red[0];
    #pragma unroll
    for (int q = 0; q < 8; ++q)
        e_lds[tid * 8 + q] = __expf(e_lds[tid * 8 + q] - Ms);
    __syncthreads();

    // per-t denominator + leaf_y (thread = (t, g), g covers 256 b's blocked)
    float dsum = 0.f, ysum = 0.f;
    #pragma unroll 4
    for (int i = 0; i < 256; ++i) {
        int b = g * 256 + i;
        float sel = (float)((mrow[b] >> t) & 1u);
        float e = sel * e_lds[b];
        dsum += e;
        ysum = fmaf(e, ylds[b], ysum);
    }
    red[tid] = dsum;
    red2[tid] = ysum;
    __syncthreads();
    if (tid < 32) {
        float den = 0.f, yv = 0.f;
        #pragma unroll
        for (int gg = 0; gg < 8; ++gg) { den += red[gg * 32 + tid]; yv += red2[gg * 32 + tid]; }
        float rd = den > 0.f ? 1.f / den : 0.f;
        rden[tid] = rd;
        out[OY + (size_t)s * NT + tid] = yv * rd;
    }
    __syncthreads();

    // chunked: alphas write + einsum accumulate (8t x 8f register tile per thread)
    const int tt = tid & 3, ff = (tid >> 2) & 7;   // bg group == g
    const float rdt = rden[t];
    float acc[8][8] = {};
    float* aout = out + OA + (size_t)s * NB * NT;
    for (int c = 0; c < 32; ++c) {
        const int b0 = c * 64;
        #pragma unroll
        for (int i = 0; i < 8; ++i) {
            int bl = g + 8 * i;
            int b = b0 + bl;
            float sel = (float)((mrow[b] >> t) & 1u);
            float alpha = sel * e_lds[b] * rdt;
            p_lds[bl * 32 + t] = alpha;
            aout[(size_t)b * NT + t] = alpha;          // coalesced 256B/wave
        }
        #pragma unroll
        for (int it = 0; it < 4; ++it) {
            int idx = tid * 4 + it * 1024;
            *(float4*)(&xs_lds[idx]) = *(const float4*)(bgX + (size_t)b0 * NF + idx);
        }
        __syncthreads();
        #pragma unroll
        for (int bb = 0; bb < 8; ++bb) {
            int bl = g + 8 * bb;
            float pv[8], xv[8];
            #pragma unroll
            for (int j = 0; j < 8; ++j) pv[j] = p_lds[bl * 32 + tt * 8 + j];
            #pragma unroll
            for (int k = 0; k < 8; ++k) xv[k] = xs_lds[bl * 64 + ff * 8 + k];
            #pragma unroll
            for (int j = 0; j < 8; ++j)
                #pragma unroll
                for (int k = 0; k < 8; ++k)
                    acc[j][k] = fmaf(pv[j], xv[k], acc[j][k]);
        }
        __syncthreads();
    }

    // tree-reduce the 8 bg-group partials, then write leaf_xs
    const int oidx = tt * 8 * 64 + ff * 8;
    float* scratch = smem;   // e/mrow/y/p regions are dead now: 8192 floats
    if (g >= 4) {
        #pragma unroll
        for (int j = 0; j < 8; ++j)
            #pragma unroll
            for (int k = 0; k < 8; ++k)
                scratch[(g - 4) * 2048 + oidx + j * 64 + k] = acc[j][k];
    }
    __syncthreads();
    if (g < 4) {
        #pragma unroll
        for (int j = 0; j < 8; ++j)
            #pragma unroll
            for (int k = 0; k < 8; ++k)
                acc[j][k] += scratch[g * 2048 + oidx + j * 64 + k];
    }
    __syncthreads();
    if (g == 2 || g == 3) {
        #pragma unroll
        for (int j = 0; j < 8; ++j)
            #pragma unroll
            for (int k = 0; k < 8; ++k)
                scratch[(g - 2) * 2048 + oidx + j * 64 + k] = acc[j][k];
    }
    __syncthreads();
    if (g < 2) {
        #pragma unroll
        for (int j = 0; j < 8; ++j)
            #pragma unroll
            for (int k = 0; k < 8; ++k)
                acc[j][k] += scratch[g * 2048 + oidx + j * 64 + k];
    }
    __syncthreads();
    if (g == 1) {
        #pragma unroll
        for (int j = 0; j < 8; ++j)
            #pragma unroll
            for (int k = 0; k < 8; ++k)
                scratch[oidx + j * 64 + k] = acc[j][k];
    }
    __syncthreads();
    if (g == 0) {
        #pragma unroll
        for (int j = 0; j < 8; ++j) {
            #pragma unroll
            for (int k = 0; k < 8; ++k)
                acc[j][k] += scratch[oidx + j * 64 + k];
            float4 v0 = make_float4(acc[j][0], acc[j][1], acc[j][2], acc[j][3]);
            float4 v1 = make_float4(acc[j][4], acc[j][5], acc[j][6], acc[j][7]);
            *(float4*)(&out[(size_t)s * NT * NF + oidx + j * 64]) = v0;
            *(float4*)(&out[(size_t)s * NT * NF + oidx + j * 64 + 4]) = v1;
        }
    }
}

extern "C" void kernel_launch(void* const* d_in, const int* in_sizes, int n_in,
                              void* d_out, int out_size, void* d_ws, size_t ws_size,
                              hipStream_t stream) {
    (void)in_sizes; (void)n_in; (void)out_size; (void)ws_size;
    const float* X   = (const float*)d_in[0];
    const float* bgX = (const float*)d_in[1];
    const float* bgy = (const float*)d_in[2];
    const void*  nh  = d_in[3];
    const float* W1  = (const float*)d_in[4];
    const float* b1v = (const float*)d_in[5];
    const float* W2  = (const float*)d_in[6];
    const float* b2v = (const float*)d_in[7];
    float* out = (float*)d_out;
    char* ws = (char*)d_ws;

    // ws layout (bytes): [flag @0][enc @4096: 2560*128 f32][dots: 512*2048 f32][pmask: 524288 u64]
    int* flag = (int*)ws;
    float* enc = (float*)(ws + 4096);
    float* Xe = enc;
    float* Be = enc + (size_t)NS * NH;
    float* dots = (float*)(ws + 4096 + (size_t)(NS + NB) * NH * 4);
    unsigned long long* pmask = (unsigned long long*)((char*)dots + (size_t)NS * NB * 4);

    const int nwords = NS * NB * NT / 64;
    detect_layout_k<<<1, 256, 0, stream>>>((const unsigned char*)nh, flag);
    pack_mask_k<<<nwords / 256, 256, 0, stream>>>(nh, flag, pmask, nwords);
    encode_k<<<NS + NB, 128, 0, stream>>>(X, bgX, W1, b1v, W2, b2v, enc);
    dots_k<<<dim3(NB / 64, NS / 64), 256, 0, stream>>>(Xe, Be, dots);
    fused_k<<<NS, 256, 0, stream>>>(dots, pmask, bgX, bgy, out);
}

// Round 4
// 124.329 us; speedup vs baseline: 1.7903x; 1.0738x over previous
//
#include <hip/hip_runtime.h>
#include <hip/hip_bf16.h>

#define NS 512
#define NB 2048
#define NT 32
#define NF 64
#define NH 128

// output float offsets: [leaf_xs (S,T,F)][leaf_y (S,T)][alphas (S,B,T)]
#define OY  ((size_t)NS * NT * NF)
#define OA  (OY + (size_t)NS * NT)

typedef __attribute__((ext_vector_type(8))) short bf16x8;
typedef __attribute__((ext_vector_type(4))) float f32x4;

__device__ __forceinline__ short f2bfs(float x) {
    __hip_bfloat16 h = __float2bfloat16(x);
    return __builtin_bit_cast(short, h);
}
__device__ __forceinline__ unsigned short f2bfu(float x) {
    __hip_bfloat16 h = __float2bfloat16(x);
    return __builtin_bit_cast(unsigned short, h);
}

// ---------- mask layout detection: 1 = 1-byte bool, 0 = int32 ----------
__global__ void detect_layout_k(const unsigned char* m, int* flag) {
    __shared__ int any1;
    if (threadIdx.x == 0) any1 = 0;
    __syncthreads();
    for (int i = threadIdx.x; i < 4096; i += blockDim.x)
        if ((i & 3) != 0 && m[i] != 0) any1 = 1;   // benign same-value race
    __syncthreads();
    if (threadIdx.x == 0) *flag = any1;
}

// bit j of result = (byte j of v != 0), j in [0,16)
__device__ __forceinline__ unsigned int pack16_bytes(uint4 v) {
    unsigned int r = 0;
    unsigned int xs[4] = {v.x, v.y, v.z, v.w};
    #pragma unroll
    for (int i = 0; i < 4; ++i) {
        unsigned int x = xs[i];
        unsigned int t = (x | ((x & 0x7F7F7F7Fu) + 0x7F7F7F7Fu)) & 0x80808080u;
        t >>= 7;                                  // nonzero flags at bits 0,8,16,24
        unsigned int n = (t | (t >> 7) | (t >> 14) | (t >> 21)) & 0xFu;
        r |= n << (i * 4);
    }
    return r;
}

// ---------- pack mask to bits: word w covers flat indices [w*64, w*64+64) ----------
// flat = s*B*T + b*T + t; per row s: u32 word index == b, bit == t.
__global__ __launch_bounds__(256) void pack_mask_k(const void* mask, const int* flag,
                                                   unsigned long long* pm, int nwords) {
    const int w = blockIdx.x * blockDim.x + threadIdx.x;
    if (w >= nwords) return;
    if (*flag) {                                   // 1-byte bool layout
        const uint4* mb = (const uint4*)mask;
        uint4 q0 = mb[(size_t)w * 4 + 0];
        uint4 q1 = mb[(size_t)w * 4 + 1];
        uint4 q2 = mb[(size_t)w * 4 + 2];
        uint4 q3 = mb[(size_t)w * 4 + 3];
        unsigned long long r =  (unsigned long long)pack16_bytes(q0)
                             | ((unsigned long long)pack16_bytes(q1) << 16)
                             | ((unsigned long long)pack16_bytes(q2) << 32)
                             | ((unsigned long long)pack16_bytes(q3) << 48);
        pm[w] = r;
    } else {                                       // int32 layout
        const uint4* mi = (const uint4*)mask;
        unsigned long long r = 0;
        #pragma unroll
        for (int i = 0; i < 16; ++i) {
            uint4 v = mi[(size_t)w * 16 + i];
            unsigned int b = (v.x ? 1u : 0u) | (v.y ? 2u : 0u) |
                             (v.z ? 4u : 0u) | (v.w ? 8u : 0u);
            r |= (unsigned long long)b << (i * 4);
        }
        pm[w] = r;
    }
}

// ---------- encode rows 0..511 = X, 512..2559 = background_X ----------
__global__ __launch_bounds__(128) void encode_k(const float* __restrict__ X,
        const float* __restrict__ bgX, const float* __restrict__ W1,
        const float* __restrict__ b1, const float* __restrict__ W2,
        const float* __restrict__ b2, float* __restrict__ enc) {
    __shared__ float xr[NF];
    __shared__ float hr[NH];
    const int row = blockIdx.x;
    const int j = threadIdx.x;
    const float* src = (row < NS) ? (X + (size_t)row * NF) : (bgX + (size_t)(row - NS) * NF);
    if (j < NF) xr[j] = src[j];
    __syncthreads();
    float acc = b1[j];
    #pragma unroll 8
    for (int f = 0; f < NF; ++f) acc = fmaf(xr[f], W1[f * NH + j], acc);
    hr[j] = tanhf(acc);
    __syncthreads();
    float acc2 = b2[j];
    #pragma unroll 8
    for (int k = 0; k < NH; ++k) acc2 = fmaf(hr[k], W2[k * NH + j], acc2);
    enc[(size_t)row * NH + j] = acc2;
}

// ---------- transpose + bf16-convert background_X: bgXT[f][b], f-major ----------
__global__ __launch_bounds__(256) void transpose_bgx_k(const float* __restrict__ bgX,
                                                       unsigned short* __restrict__ bgXT) {
    __shared__ float t_lds[64][65];
    const int b0 = blockIdx.x * 64;
    const int tid = threadIdx.x;
    #pragma unroll
    for (int it = 0; it < 4; ++it) {
        int idx = (it * 256 + tid) * 4;
        int r = idx >> 6, c = idx & 63;
        *(float4*)(&t_lds[r][c]) = *(const float4*)(bgX + (size_t)(b0 + r) * NF + c);
    }
    __syncthreads();
    const int f = tid >> 2, sg = (tid & 3) * 16;
    union { unsigned short u[16]; uint4 q[2]; } pk;
    #pragma unroll
    for (int i = 0; i < 16; ++i) pk.u[i] = f2bfu(t_lds[sg + i][f]);
    uint4* dst = (uint4*)(bgXT + (size_t)f * NB + b0 + sg);
    dst[0] = pk.q[0];
    dst[1] = pk.q[1];
}

// ---------- dots = X_enc @ bg_enc^T, 64x64 tiles, K=128 in two 64-slices ----------
__global__ __launch_bounds__(256) void dots_k(const float* __restrict__ Xe,
        const float* __restrict__ Be, float* __restrict__ dots) {
    __shared__ float At[64 * 68];
    __shared__ float Bt[64 * 68];
    const int s0 = blockIdx.y * 64, b0 = blockIdx.x * 64;
    const int tid = threadIdx.x;
    const int ts = tid & 15, tb = tid >> 4;
    float acc[4][4] = {};
    for (int kt = 0; kt < 2; ++kt) {
        __syncthreads();
        #pragma unroll
        for (int it = 0; it < 4; ++it) {
            int idx = tid * 4 + it * 1024;
            int r = idx >> 6, k = idx & 63;
            *(float4*)(&At[r * 68 + k]) = *(const float4*)(Xe + (size_t)(s0 + r) * NH + kt * 64 + k);
            *(float4*)(&Bt[r * 68 + k]) = *(const float4*)(Be + (size_t)(b0 + r) * NH + kt * 64 + k);
        }
        __syncthreads();
        #pragma unroll 4
        for (int k = 0; k < 64; ++k) {
            float a[4], bv[4];
            #pragma unroll
            for (int i = 0; i < 4; ++i) a[i] = At[(ts + 16 * i) * 68 + k];
            #pragma unroll
            for (int jj = 0; jj < 4; ++jj) bv[jj] = Bt[(tb * 4 + jj) * 68 + k];
            #pragma unroll
            for (int i = 0; i < 4; ++i)
                #pragma unroll
                for (int jj = 0; jj < 4; ++jj)
                    acc[i][jj] = fmaf(a[i], bv[jj], acc[i][jj]);
        }
    }
    #pragma unroll
    for (int i = 0; i < 4; ++i) {
        float4 v = make_float4(acc[i][0], acc[i][1], acc[i][2], acc[i][3]);
        *(float4*)(&dots[(size_t)(s0 + ts + 16 * i) * NB + b0 + tb * 4]) = v;
    }
}

// ---------- fused softmax + alphas + leaf_y + MFMA leaf_xs, one block per s ----------
__global__ __launch_bounds__(256) void fused_k(const float* __restrict__ dots,
        const unsigned long long* __restrict__ pmask,
        const unsigned short* __restrict__ bgXT, const float* __restrict__ bgy,
        float* __restrict__ out) {
    __shared__ float e_lds[NB];            // dots -> exp(d - M)
    __shared__ unsigned int mrow[NB];      // mrow[b] bit t
    __shared__ float ylds[NB];             // bg_y
    __shared__ float red[256];
    __shared__ float red2[256];
    __shared__ float rden_l[NT];
    __shared__ float part[3 * NT * NF];    // cross-wave einsum partials

    const int s = blockIdx.x;
    const int tid = threadIdx.x;
    const int lane = tid & 63, w = tid >> 6;
    const int t = tid & 31, g = tid >> 5;

    // ---- phase 1: stage + softmax pieces ----
    const float* drow = dots + (size_t)s * NB;
    float4 d0 = *(const float4*)(drow + tid * 8);
    float4 d1 = *(const float4*)(drow + tid * 8 + 4);
    *(float4*)(&e_lds[tid * 8]) = d0;
    *(float4*)(&e_lds[tid * 8 + 4]) = d1;
    red[tid] = fmaxf(fmaxf(fmaxf(d0.x, d0.y), fmaxf(d0.z, d0.w)),
                     fmaxf(fmaxf(d1.x, d1.y), fmaxf(d1.z, d1.w)));
    const uint4* pmrow = (const uint4*)((const unsigned int*)pmask + (size_t)s * NB);
    #pragma unroll
    for (int it = 0; it < 2; ++it)
        *(uint4*)(&mrow[(tid + it * 256) * 4]) = pmrow[tid + it * 256];
    #pragma unroll
    for (int it = 0; it < 2; ++it)
        *(float4*)(&ylds[(tid + it * 256) * 4]) = *(const float4*)(bgy + (tid + it * 256) * 4);
    __syncthreads();
    for (int off = 128; off > 0; off >>= 1) {
        if (tid < off) red[tid] = fmaxf(red[tid], red[tid + off]);
        __syncthreads();
    }
    const float Ms = red[0];
    #pragma unroll
    for (int q = 0; q < 8; ++q)
        e_lds[tid * 8 + q] = __expf(e_lds[tid * 8 + q] - Ms);
    __syncthreads();

    // per-t denominator + leaf_y (thread = (t, g), g covers 256 b's blocked)
    float dsum = 0.f, ysum = 0.f;
    #pragma unroll 4
    for (int i = 0; i < 256; ++i) {
        int b = g * 256 + i;
        float sel = (float)((mrow[b] >> t) & 1u);
        float e = sel * e_lds[b];
        dsum += e;
        ysum = fmaf(e, ylds[b], ysum);
    }
    red[tid] = dsum;
    red2[tid] = ysum;
    __syncthreads();
    if (tid < 32) {
        float den = 0.f, yv = 0.f;
        #pragma unroll
        for (int gg = 0; gg < 8; ++gg) { den += red[gg * 32 + tid]; yv += red2[gg * 32 + tid]; }
        float rd = den > 0.f ? 1.f / den : 0.f;
        rden_l[tid] = rd;
        out[OY + (size_t)s * NT + tid] = yv * rd;
    }
    __syncthreads();

    // ---- phase 2: alphas write, pure streaming (1KB/wave/instr) ----
    {
        const int bq = tid >> 3, tq = tid & 7;
        float rd4[4];
        #pragma unroll
        for (int k = 0; k < 4; ++k) rd4[k] = rden_l[tq * 4 + k];
        float* aout = out + OA + (size_t)s * NB * NT;
        #pragma unroll 2
        for (int it = 0; it < 64; ++it) {
            int b = it * 32 + bq;
            float e = e_lds[b];
            unsigned int m = mrow[b] >> (tq * 4);
            float4 v;
            v.x = (m & 1u) ? e * rd4[0] : 0.f;
            v.y = (m & 2u) ? e * rd4[1] : 0.f;
            v.z = (m & 4u) ? e * rd4[2] : 0.f;
            v.w = (m & 8u) ? e * rd4[3] : 0.f;
            *(float4*)(aout + (size_t)b * NT + tq * 4) = v;
        }
    }

    // ---- phase 3: MFMA einsum, K split over 4 waves (512 b each) ----
    const int lo = lane & 15, hi = lane >> 4;
    const float rdm0 = rden_l[lo], rdm1 = rden_l[16 + lo];
    f32x4 acc[2][4] = {};
    const unsigned short* bptr = bgXT + (size_t)lo * NB + w * 512 + hi * 8;
    #pragma unroll 2
    for (int ks = 0; ks < 16; ++ks) {
        const int bb = w * 512 + ks * 32 + hi * 8;
        float4 e0 = *(const float4*)(&e_lds[bb]);
        float4 e1 = *(const float4*)(&e_lds[bb + 4]);
        uint4 m0 = *(const uint4*)(&mrow[bb]);
        uint4 m1 = *(const uint4*)(&mrow[bb + 4]);
        float ev[8] = {e0.x, e0.y, e0.z, e0.w, e1.x, e1.y, e1.z, e1.w};
        unsigned int mv[8] = {m0.x, m0.y, m0.z, m0.w, m1.x, m1.y, m1.z, m1.w};
        bf16x8 a0, a1;
        #pragma unroll
        for (int j = 0; j < 8; ++j) {
            unsigned int mj = mv[j] >> lo;
            a0[j] = f2bfs((mj & 1u) ? ev[j] * rdm0 : 0.f);
            a1[j] = f2bfs((mj & 0x10000u) ? ev[j] * rdm1 : 0.f);
        }
        #pragma unroll
        for (int n = 0; n < 4; ++n) {
            uint4 bv = *(const uint4*)(bptr + (size_t)n * 16 * NB + ks * 32);
            bf16x8 bfr = __builtin_bit_cast(bf16x8, bv);
            acc[0][n] = __builtin_amdgcn_mfma_f32_16x16x32_bf16(a0, bfr, acc[0][n], 0, 0, 0);
            acc[1][n] = __builtin_amdgcn_mfma_f32_16x16x32_bf16(a1, bfr, acc[1][n], 0, 0, 0);
        }
    }

    // ---- phase 4: cross-wave reduce + leaf_xs write ----
    if (w > 0) {
        #pragma unroll
        for (int m = 0; m < 2; ++m)
            #pragma unroll
            for (int n = 0; n < 4; ++n)
                #pragma unroll
                for (int r = 0; r < 4; ++r) {
                    int tt = m * 16 + hi * 4 + r, ff = n * 16 + lo;
                    part[(w - 1) * (NT * NF) + tt * NF + ff] = acc[m][n][r];
                }
    }
    __syncthreads();
    if (w == 0) {
        float* xout = out + (size_t)s * NT * NF;
        #pragma unroll
        for (int m = 0; m < 2; ++m)
            #pragma unroll
            for (int n = 0; n < 4; ++n)
                #pragma unroll
                for (int r = 0; r < 4; ++r) {
                    int tt = m * 16 + hi * 4 + r, ff = n * 16 + lo;
                    int o = tt * NF + ff;
                    xout[o] = acc[m][n][r] + part[o] + part[NT * NF + o] + part[2 * NT * NF + o];
                }
    }
}

extern "C" void kernel_launch(void* const* d_in, const int* in_sizes, int n_in,
                              void* d_out, int out_size, void* d_ws, size_t ws_size,
                              hipStream_t stream) {
    (void)in_sizes; (void)n_in; (void)out_size; (void)ws_size;
    const float* X   = (const float*)d_in[0];
    const float* bgX = (const float*)d_in[1];
    const float* bgy = (const float*)d_in[2];
    const void*  nh  = d_in[3];
    const float* W1  = (const float*)d_in[4];
    const float* b1v = (const float*)d_in[5];
    const float* W2  = (const float*)d_in[6];
    const float* b2v = (const float*)d_in[7];
    float* out = (float*)d_out;
    char* ws = (char*)d_ws;

    // ws layout (bytes): [flag @0 pad 4096][enc: 2560*128 f32][dots: 512*2048 f32]
    //                    [pmask: 524288 u64][bgXT: 64*2048 u16]
    int* flag = (int*)ws;
    float* enc = (float*)(ws + 4096);
    float* Xe = enc;
    float* Be = enc + (size_t)NS * NH;
    float* dots = (float*)(ws + 4096 + (size_t)(NS + NB) * NH * 4);
    unsigned long long* pmask = (unsigned long long*)((char*)dots + (size_t)NS * NB * 4);
    unsigned short* bgXT = (unsigned short*)((char*)pmask + (size_t)NS * NB * NT / 64 * 8);

    const int nwords = NS * NB * NT / 64;
    detect_layout_k<<<1, 256, 0, stream>>>((const unsigned char*)nh, flag);
    pack_mask_k<<<nwords / 256, 256, 0, stream>>>(nh, flag, pmask, nwords);
    encode_k<<<NS + NB, 128, 0, stream>>>(X, bgX, W1, b1v, W2, b2v, enc);
    transpose_bgx_k<<<NB / 64, 256, 0, stream>>>(bgX, bgXT);
    dots_k<<<dim3(NB / 64, NS / 64), 256, 0, stream>>>(Xe, Be, dots);
    fused_k<<<NS, 256, 0, stream>>>(dots, pmask, bgXT, bgy, out);
}

// Round 5
// 109.801 us; speedup vs baseline: 2.0272x; 1.1323x over previous
//
#include <hip/hip_runtime.h>
#include <hip/hip_bf16.h>

#define NS 512
#define NB 2048
#define NT 32
#define NF 64
#define NH 128

// output float offsets: [leaf_xs (S,T,F)][leaf_y (S,T)][alphas (S,B,T)]
#define OY  ((size_t)NS * NT * NF)
#define OA  (OY + (size_t)NS * NT)

typedef __attribute__((ext_vector_type(8))) short bf16x8;
typedef __attribute__((ext_vector_type(4))) float f32x4;

__device__ __forceinline__ short f2bfs(float x) {
    __hip_bfloat16 h = __float2bfloat16(x);
    return __builtin_bit_cast(short, h);
}
__device__ __forceinline__ unsigned short f2bfu(float x) {
    __hip_bfloat16 h = __float2bfloat16(x);
    return __builtin_bit_cast(unsigned short, h);
}

// ---------- mask layout detection: 1 = 1-byte bool, 0 = int32 ----------
__global__ void detect_layout_k(const unsigned char* m, int* flag) {
    __shared__ int any1;
    if (threadIdx.x == 0) any1 = 0;
    __syncthreads();
    for (int i = threadIdx.x; i < 4096; i += blockDim.x)
        if ((i & 3) != 0 && m[i] != 0) any1 = 1;   // benign same-value race
    __syncthreads();
    if (threadIdx.x == 0) *flag = any1;
}

// bit j of result = (byte j of v != 0), j in [0,16)
__device__ __forceinline__ unsigned int pack16_bytes(uint4 v) {
    unsigned int r = 0;
    unsigned int xs[4] = {v.x, v.y, v.z, v.w};
    #pragma unroll
    for (int i = 0; i < 4; ++i) {
        unsigned int x = xs[i];
        unsigned int t = (x | ((x & 0x7F7F7F7Fu) + 0x7F7F7F7Fu)) & 0x80808080u;
        t >>= 7;                                  // nonzero flags at bits 0,8,16,24
        unsigned int n = (t | (t >> 7) | (t >> 14) | (t >> 21)) & 0xFu;
        r |= n << (i * 4);
    }
    return r;
}

// ---------- pack mask to bits: word w covers flat indices [w*64, w*64+64) ----------
// flat = s*B*T + b*T + t; per row s: u32 word index == b, bit == t.
__global__ __launch_bounds__(256) void pack_mask_k(const void* mask, const int* flag,
                                                   unsigned long long* pm, int nwords) {
    const int w = blockIdx.x * blockDim.x + threadIdx.x;
    if (w >= nwords) return;
    if (*flag) {                                   // 1-byte bool layout
        const uint4* mb = (const uint4*)mask;
        uint4 q0 = mb[(size_t)w * 4 + 0];
        uint4 q1 = mb[(size_t)w * 4 + 1];
        uint4 q2 = mb[(size_t)w * 4 + 2];
        uint4 q3 = mb[(size_t)w * 4 + 3];
        unsigned long long r =  (unsigned long long)pack16_bytes(q0)
                             | ((unsigned long long)pack16_bytes(q1) << 16)
                             | ((unsigned long long)pack16_bytes(q2) << 32)
                             | ((unsigned long long)pack16_bytes(q3) << 48);
        pm[w] = r;
    } else {                                       // int32 layout
        const uint4* mi = (const uint4*)mask;
        unsigned long long r = 0;
        #pragma unroll
        for (int i = 0; i < 16; ++i) {
            uint4 v = mi[(size_t)w * 16 + i];
            unsigned int b = (v.x ? 1u : 0u) | (v.y ? 2u : 0u) |
                             (v.z ? 4u : 0u) | (v.w ? 8u : 0u);
            r |= (unsigned long long)b << (i * 4);
        }
        pm[w] = r;
    }
}

// ---------- encode rows 0..511 = X, 512..2559 = background_X ----------
__global__ __launch_bounds__(128) void encode_k(const float* __restrict__ X,
        const float* __restrict__ bgX, const float* __restrict__ W1,
        const float* __restrict__ b1, const float* __restrict__ W2,
        const float* __restrict__ b2, float* __restrict__ enc) {
    __shared__ float xr[NF];
    __shared__ float hr[NH];
    const int row = blockIdx.x;
    const int j = threadIdx.x;
    const float* src = (row < NS) ? (X + (size_t)row * NF) : (bgX + (size_t)(row - NS) * NF);
    if (j < NF) xr[j] = src[j];
    __syncthreads();
    float acc = b1[j];
    #pragma unroll 8
    for (int f = 0; f < NF; ++f) acc = fmaf(xr[f], W1[f * NH + j], acc);
    hr[j] = tanhf(acc);
    __syncthreads();
    float acc2 = b2[j];
    #pragma unroll 8
    for (int k = 0; k < NH; ++k) acc2 = fmaf(hr[k], W2[k * NH + j], acc2);
    enc[(size_t)row * NH + j] = acc2;
}

// ---------- transpose + bf16-convert background_X: bgXT[f][b], f-major ----------
__global__ __launch_bounds__(256) void transpose_bgx_k(const float* __restrict__ bgX,
                                                       unsigned short* __restrict__ bgXT) {
    __shared__ float t_lds[64][65];
    const int b0 = blockIdx.x * 64;
    const int tid = threadIdx.x;
    #pragma unroll
    for (int it = 0; it < 4; ++it) {
        int idx = (it * 256 + tid) * 4;
        int r = idx >> 6, c = idx & 63;
        *(float4*)(&t_lds[r][c]) = *(const float4*)(bgX + (size_t)(b0 + r) * NF + c);
    }
    __syncthreads();
    const int f = tid >> 2, sg = (tid & 3) * 16;
    union { unsigned short u[16]; uint4 q[2]; } pk;
    #pragma unroll
    for (int i = 0; i < 16; ++i) pk.u[i] = f2bfu(t_lds[sg + i][f]);
    uint4* dst = (uint4*)(bgXT + (size_t)f * NB + b0 + sg);
    dst[0] = pk.q[0];
    dst[1] = pk.q[1];
}

// ---------- dots = X_enc @ bg_enc^T, 64x64 tiles, K=128 in two 64-slices ----------
__global__ __launch_bounds__(256) void dots_k(const float* __restrict__ Xe,
        const float* __restrict__ Be, float* __restrict__ dots) {
    __shared__ float At[64 * 68];
    __shared__ float Bt[64 * 68];
    const int s0 = blockIdx.y * 64, b0 = blockIdx.x * 64;
    const int tid = threadIdx.x;
    const int ts = tid & 15, tb = tid >> 4;
    float acc[4][4] = {};
    for (int kt = 0; kt < 2; ++kt) {
        __syncthreads();
        #pragma unroll
        for (int it = 0; it < 4; ++it) {
            int idx = tid * 4 + it * 1024;
            int r = idx >> 6, k = idx & 63;
            *(float4*)(&At[r * 68 + k]) = *(const float4*)(Xe + (size_t)(s0 + r) * NH + kt * 64 + k);
            *(float4*)(&Bt[r * 68 + k]) = *(const float4*)(Be + (size_t)(b0 + r) * NH + kt * 64 + k);
        }
        __syncthreads();
        #pragma unroll 4
        for (int k = 0; k < 64; ++k) {
            float a[4], bv[4];
            #pragma unroll
            for (int i = 0; i < 4; ++i) a[i] = At[(ts + 16 * i) * 68 + k];
            #pragma unroll
            for (int jj = 0; jj < 4; ++jj) bv[jj] = Bt[(tb * 4 + jj) * 68 + k];
            #pragma unroll
            for (int i = 0; i < 4; ++i)
                #pragma unroll
                for (int jj = 0; jj < 4; ++jj)
                    acc[i][jj] = fmaf(a[i], bv[jj], acc[i][jj]);
        }
    }
    #pragma unroll
    for (int i = 0; i < 4; ++i) {
        float4 v = make_float4(acc[i][0], acc[i][1], acc[i][2], acc[i][3]);
        *(float4*)(&dots[(size_t)(s0 + ts + 16 * i) * NB + b0 + tb * 4]) = v;
    }
}

// ---------- softmax stats + leaf_y + MFMA leaf_xs, one block per s ----------
// Overwrites dots row s in-place with e = exp(d - Ms); writes rden[s][32].
__global__ __launch_bounds__(256) void fusedA_k(float* __restrict__ dots,
        const unsigned long long* __restrict__ pmask,
        const unsigned short* __restrict__ bgXT, const float* __restrict__ bgy,
        float* __restrict__ rden_g, float* __restrict__ out) {
    __shared__ float e_lds[NB];            // dots -> exp(d - M)
    __shared__ unsigned int mrow[NB];      // mrow[b] bit t
    __shared__ float ylds[NB];             // bg_y
    __shared__ float red[256];
    __shared__ float red2[256];
    __shared__ float rden_l[NT];
    __shared__ float part[3 * NT * NF];    // cross-wave einsum partials

    const int s = blockIdx.x;
    const int tid = threadIdx.x;
    const int lane = tid & 63, w = tid >> 6;
    const int t = tid & 31, g = tid >> 5;

    // ---- phase 1: stage + softmax stats ----
    float* drow = dots + (size_t)s * NB;
    float4 d0 = *(const float4*)(drow + tid * 8);
    float4 d1 = *(const float4*)(drow + tid * 8 + 4);
    *(float4*)(&e_lds[tid * 8]) = d0;
    *(float4*)(&e_lds[tid * 8 + 4]) = d1;
    red[tid] = fmaxf(fmaxf(fmaxf(d0.x, d0.y), fmaxf(d0.z, d0.w)),
                     fmaxf(fmaxf(d1.x, d1.y), fmaxf(d1.z, d1.w)));
    const uint4* pmrow = (const uint4*)((const unsigned int*)pmask + (size_t)s * NB);
    #pragma unroll
    for (int it = 0; it < 2; ++it)
        *(uint4*)(&mrow[(tid + it * 256) * 4]) = pmrow[tid + it * 256];
    #pragma unroll
    for (int it = 0; it < 2; ++it)
        *(float4*)(&ylds[(tid + it * 256) * 4]) = *(const float4*)(bgy + (tid + it * 256) * 4);
    __syncthreads();
    for (int off = 128; off > 0; off >>= 1) {
        if (tid < off) red[tid] = fmaxf(red[tid], red[tid + off]);
        __syncthreads();
    }
    const float Ms = red[0];
    float ev[8];
    #pragma unroll
    for (int q = 0; q < 8; ++q) {
        ev[q] = __expf(e_lds[tid * 8 + q] - Ms);
        e_lds[tid * 8 + q] = ev[q];
    }
    // write e back in-place (dots is regenerated by dots_k every call)
    *(float4*)(drow + tid * 8)     = make_float4(ev[0], ev[1], ev[2], ev[3]);
    *(float4*)(drow + tid * 8 + 4) = make_float4(ev[4], ev[5], ev[6], ev[7]);
    __syncthreads();

    // per-t denominator + leaf_y (thread = (t, g), g covers 256 b's blocked)
    float dsum = 0.f, ysum = 0.f;
    #pragma unroll 4
    for (int i = 0; i < 256; ++i) {
        int b = g * 256 + i;
        float sel = (float)((mrow[b] >> t) & 1u);
        float e = sel * e_lds[b];
        dsum += e;
        ysum = fmaf(e, ylds[b], ysum);
    }
    red[tid] = dsum;
    red2[tid] = ysum;
    __syncthreads();
    if (tid < 32) {
        float den = 0.f, yv = 0.f;
        #pragma unroll
        for (int gg = 0; gg < 8; ++gg) { den += red[gg * 32 + tid]; yv += red2[gg * 32 + tid]; }
        float rd = den > 0.f ? 1.f / den : 0.f;
        rden_l[tid] = rd;
        rden_g[(size_t)s * NT + tid] = rd;
        out[OY + (size_t)s * NT + tid] = yv * rd;
    }
    __syncthreads();

    // ---- phase 2: MFMA einsum, K split over 4 waves (512 b each) ----
    const int lo = lane & 15, hi = lane >> 4;
    const float rdm0 = rden_l[lo], rdm1 = rden_l[16 + lo];
    f32x4 acc[2][4] = {};
    const unsigned short* bptr = bgXT + (size_t)lo * NB + w * 512 + hi * 8;
    #pragma unroll 2
    for (int ks = 0; ks < 16; ++ks) {
        const int bb = w * 512 + ks * 32 + hi * 8;
        float4 e0 = *(const float4*)(&e_lds[bb]);
        float4 e1 = *(const float4*)(&e_lds[bb + 4]);
        uint4 m0 = *(const uint4*)(&mrow[bb]);
        uint4 m1 = *(const uint4*)(&mrow[bb + 4]);
        float evv[8] = {e0.x, e0.y, e0.z, e0.w, e1.x, e1.y, e1.z, e1.w};
        unsigned int mv[8] = {m0.x, m0.y, m0.z, m0.w, m1.x, m1.y, m1.z, m1.w};
        bf16x8 a0, a1;
        #pragma unroll
        for (int j = 0; j < 8; ++j) {
            unsigned int mj = mv[j] >> lo;
            a0[j] = f2bfs((mj & 1u) ? evv[j] * rdm0 : 0.f);
            a1[j] = f2bfs((mj & 0x10000u) ? evv[j] * rdm1 : 0.f);
        }
        #pragma unroll
        for (int n = 0; n < 4; ++n) {
            uint4 bv = *(const uint4*)(bptr + (size_t)n * 16 * NB + ks * 32);
            bf16x8 bfr = __builtin_bit_cast(bf16x8, bv);
            acc[0][n] = __builtin_amdgcn_mfma_f32_16x16x32_bf16(a0, bfr, acc[0][n], 0, 0, 0);
            acc[1][n] = __builtin_amdgcn_mfma_f32_16x16x32_bf16(a1, bfr, acc[1][n], 0, 0, 0);
        }
    }

    // ---- phase 3: cross-wave reduce + leaf_xs write ----
    if (w > 0) {
        #pragma unroll
        for (int m = 0; m < 2; ++m)
            #pragma unroll
            for (int n = 0; n < 4; ++n)
                #pragma unroll
                for (int r = 0; r < 4; ++r) {
                    int tt = m * 16 + hi * 4 + r, ff = n * 16 + lo;
                    part[(w - 1) * (NT * NF) + tt * NF + ff] = acc[m][n][r];
                }
    }
    __syncthreads();
    if (w == 0) {
        float* xout = out + (size_t)s * NT * NF;
        #pragma unroll
        for (int m = 0; m < 2; ++m)
            #pragma unroll
            for (int n = 0; n < 4; ++n)
                #pragma unroll
                for (int r = 0; r < 4; ++r) {
                    int tt = m * 16 + hi * 4 + r, ff = n * 16 + lo;
                    int o = tt * NF + ff;
                    xout[o] = acc[m][n][r] + part[o] + part[NT * NF + o] + part[2 * NT * NF + o];
                }
    }
}

// ---------- alphas streaming write: 2048 blocks, full occupancy ----------
__global__ __launch_bounds__(256) void alphas_k(const float* __restrict__ e,
        const unsigned int* __restrict__ pmask32, const float* __restrict__ rden_g,
        float* __restrict__ out) {
    const int tid = threadIdx.x;
    const int blk = blockIdx.x;               // 2048 blocks: (s, quarter)
    const int s = blk >> 2;
    const int tq = tid & 7;
    const f32x4 rd4 = *(const f32x4*)(rden_g + (size_t)s * NT + tq * 4);
    const float* erow = e + (size_t)s * NB;
    const unsigned int* mr = pmask32 + (size_t)s * NB;
    float* aout = out + OA + (size_t)s * NB * NT;
    const int bbase = (blk & 3) * 512;
    #pragma unroll 4
    for (int it = 0; it < 16; ++it) {
        int fidx = it * 256 + tid;             // float4 index within 512-b chunk
        int b = bbase + (fidx >> 3);
        float evb = erow[b];
        unsigned int m = mr[b] >> (tq * 4);
        f32x4 v;
        v.x = (m & 1u) ? evb * rd4.x : 0.f;
        v.y = (m & 2u) ? evb * rd4.y : 0.f;
        v.z = (m & 4u) ? evb * rd4.z : 0.f;
        v.w = (m & 8u) ? evb * rd4.w : 0.f;
        __builtin_nontemporal_store(v, (f32x4*)(aout + (size_t)b * NT + tq * 4));
    }
}

extern "C" void kernel_launch(void* const* d_in, const int* in_sizes, int n_in,
                              void* d_out, int out_size, void* d_ws, size_t ws_size,
                              hipStream_t stream) {
    (void)in_sizes; (void)n_in; (void)out_size; (void)ws_size;
    const float* X   = (const float*)d_in[0];
    const float* bgX = (const float*)d_in[1];
    const float* bgy = (const float*)d_in[2];
    const void*  nh  = d_in[3];
    const float* W1  = (const float*)d_in[4];
    const float* b1v = (const float*)d_in[5];
    const float* W2  = (const float*)d_in[6];
    const float* b2v = (const float*)d_in[7];
    float* out = (float*)d_out;
    char* ws = (char*)d_ws;

    // ws layout (bytes): [flag @0 pad 4096][enc: 2560*128 f32][dots/e: 512*2048 f32]
    //                    [pmask: 524288 u64][bgXT: 64*2048 u16][rden: 512*32 f32]
    int* flag = (int*)ws;
    float* enc = (float*)(ws + 4096);
    float* Xe = enc;
    float* Be = enc + (size_t)NS * NH;
    float* dots = (float*)(ws + 4096 + (size_t)(NS + NB) * NH * 4);
    unsigned long long* pmask = (unsigned long long*)((char*)dots + (size_t)NS * NB * 4);
    unsigned short* bgXT = (unsigned short*)((char*)pmask + (size_t)NS * NB * NT / 64 * 8);
    float* rden_g = (float*)((char*)bgXT + (size_t)NF * NB * 2);

    const int nwords = NS * NB * NT / 64;
    detect_layout_k<<<1, 256, 0, stream>>>((const unsigned char*)nh, flag);
    pack_mask_k<<<nwords / 256, 256, 0, stream>>>(nh, flag, pmask, nwords);
    encode_k<<<NS + NB, 128, 0, stream>>>(X, bgX, W1, b1v, W2, b2v, enc);
    transpose_bgx_k<<<NB / 64, 256, 0, stream>>>(bgX, bgXT);
    dots_k<<<dim3(NB / 64, NS / 64), 256, 0, stream>>>(Xe, Be, dots);
    fusedA_k<<<NS, 256, 0, stream>>>(dots, pmask, bgXT, bgy, rden_g, out);
    alphas_k<<<NS * 4, 256, 0, stream>>>(dots, (const unsigned int*)pmask, rden_g, out);
}